// Round 7
// baseline (582.954 us; speedup 1.0000x reference)
//
#include <hip/hip_runtime.h>

#define N_NODES  100000
#define N_EDGES  1600000
#define HIDDEN   128
#define STEPS    4
#define N_GRAPHS 64
#define NBUCK    256
#define BWID     391   // nodes per bucket: 256*391 = 100096 >= 100000 (<512 -> 9 bits)
#define BCAP     7168  // fixed ebuf slots per bucket (mean 6250, +11 sigma)

typedef unsigned short u16;
typedef unsigned int   u32;
typedef unsigned long long u64;
typedef __attribute__((ext_vector_type(8))) short bf16x8;
typedef __attribute__((ext_vector_type(4))) float f32x4;
typedef __attribute__((ext_vector_type(2))) float f32x2;

__device__ inline u16 f2bf(float f) {
  u32 u = __float_as_uint(f);
  u = (u + 0x7FFFu + ((u >> 16) & 1u)) >> 16;  // RTNE
  return (u16)u;
}
__device__ inline float bf2f(u16 b) { return __uint_as_float(((u32)b) << 16); }

// rcp-based activations: no IEEE division sequence, no clamps.
__device__ inline float rcp_f(float x) { return __builtin_amdgcn_rcpf(x); }
__device__ inline float sig_f(float x) { return rcp_f(1.f + __expf(-x)); }
__device__ inline float tanh_f(float x) { return 1.f - 2.f * rcp_f(1.f + __expf(2.f * x)); }

// ---------------- CSR build (bucketed multisplit, fixed-capacity buckets) ----------------
__global__ __launch_bounds__(1024) void k_part(const int* __restrict__ esrc,
                                               const int* __restrict__ edst,
                                               int* __restrict__ gcursor,
                                               u32* __restrict__ ebuf) {
  __shared__ int hist[16][NBUCK];   // 16 KB
  __shared__ int base[16][NBUCK];   // 16 KB
  int tid = threadIdx.x;
  int wv  = tid >> 6;
  #pragma unroll
  for (int i = 0; i < 4; ++i) ((int*)hist)[tid + i * 1024] = 0;
  __syncthreads();
  int e0 = blockIdx.x * 4096;
  int sv[4], dv[4], bk[4], rk[4];
  #pragma unroll
  for (int i = 0; i < 4; ++i) {
    int e = e0 + i * 1024 + tid;
    if (e < N_EDGES) {
      sv[i] = esrc[e];
      dv[i] = edst[e];
      bk[i] = (int)((u32)dv[i] / (u32)BWID);
      rk[i] = atomicAdd(&hist[wv][bk[i]], 1);
    } else bk[i] = -1;
  }
  __syncthreads();
  if (tid < NBUCK) {
    int c[16];
    int sum = 0;
    #pragma unroll
    for (int w = 0; w < 16; ++w) { c[w] = hist[w][tid]; sum += c[w]; }
    int g = atomicAdd(&gcursor[tid], sum);
    #pragma unroll
    for (int w = 0; w < 16; ++w) { base[w][tid] = g; g += c[w]; }
  }
  __syncthreads();
  #pragma unroll
  for (int i = 0; i < 4; ++i) {
    if (bk[i] >= 0) {
      int pos = bk[i] * BCAP + base[wv][bk[i]] + rk[i];
      ebuf[pos] = ((u32)(dv[i] - bk[i] * BWID) << 17) | (u32)sv[i];
    }
  }
}

// Scan bucket counts -> ebase; also zero the pool accumulator (saves a dispatch).
__global__ void k_bscan(const int* __restrict__ gcursor, int* __restrict__ ebase,
                        float* __restrict__ acc) {
  __shared__ int buf[NBUCK];
  int t = threadIdx.x;
  int v = gcursor[t];
  buf[t] = v;
  __syncthreads();
  for (int off = 1; off < NBUCK; off <<= 1) {
    int u = 0;
    if (t >= off) u = buf[t - off];
    __syncthreads();
    buf[t] += u;
    __syncthreads();
  }
  ebase[t] = buf[t] - v;
  if (t == NBUCK - 1) ebase[NBUCK] = buf[t];
  for (int i = t; i < N_GRAPHS * HIDDEN; i += NBUCK) acc[i] = 0.f;
}

__global__ __launch_bounds__(1024) void k_csr(const u32* __restrict__ ebuf,
                                              const int* __restrict__ ebase,
                                              int* __restrict__ offs,
                                              int* __restrict__ csr) {
  __shared__ int lcnt[512];
  __shared__ int lofs[512];
  int b = blockIdx.x, tid = threadIdx.x;
  int n0 = b * BWID;
  int n1 = min(n0 + BWID, N_NODES);
  int nn = n1 - n0;
  int e0 = ebase[b];
  int cnt = ebase[b + 1] - e0;
  const u32* ebase_p = ebuf + (size_t)b * BCAP;
  if (tid < 512) lcnt[tid] = 0;
  __syncthreads();
  for (int e = tid; e < cnt; e += 1024) {
    int dst = (int)(ebase_p[e] >> 17);   // bucket-local
    atomicAdd(&lcnt[dst], 1);
  }
  __syncthreads();
  if (tid < 512) lofs[tid] = lcnt[tid];
  __syncthreads();
  for (int off = 1; off < 512; off <<= 1) {
    int v = 0;
    if (tid < 512 && tid >= off) v = lofs[tid - off];
    __syncthreads();
    if (tid < 512 && tid >= off) lofs[tid] += v;
    __syncthreads();
  }
  int nodeoff = 0;
  if (tid < 512) nodeoff = e0 + lofs[tid] - lcnt[tid];  // exclusive
  if (tid < 512) lofs[tid] = nodeoff;                   // reuse as cursor
  if (tid < nn) offs[n0 + tid] = nodeoff;
  if (b == 0 && tid == 0) offs[N_NODES] = N_EDGES;
  __syncthreads();
  for (int e = tid; e < cnt; e += 1024) {
    u32 p = ebase_p[e];
    int src = (int)(p & 0x1FFFFu);
    int dst = (int)(p >> 17);
    int pos = atomicAdd(&lofs[dst], 1);
    csr[pos] = src;
  }
}

// ---------------- combined weight build ----------------
__global__ void k_wb(const float* __restrict__ W, const float* __restrict__ w_ih,
                     const float* __restrict__ w_hh, u16* __restrict__ bsw) {
  __shared__ float wrow[128];
  int b = blockIdx.x, st = b >> 8, k = b & 255, t = threadIdx.x;
  if (k < 128) wrow[t] = W[(st * 128 + k) * 128 + t];
  __syncthreads();
  int kc = k >> 5, quad = (k >> 3) & 3, kl = k & 7;
  u16* base = bsw + (size_t)st * 131072 + kc * 16384;
  #pragma unroll
  for (int gq = 0; gq < 4; ++gq) {
    int c = gq * 128 + t;
    float v;
    if (k < 128) {
      if (c < 384) {
        const float* wr = w_ih + c * 128;
        float sacc = 0.f;
        for (int j = 0; j < 128; ++j) sacc += wrow[j] * wr[j];
        v = sacc;
      } else v = 0.f;
    } else {
      int kk = k - 128;
      if (c < 256)      v = w_hh[c * 128 + kk];
      else if (c < 384) v = 0.f;
      else              v = w_hh[(c - 128) * 128 + kk];
    }
    int gi = c >> 7, cw = c & 127;
    int wv = cw >> 5, hu = (cw >> 4) & 1, nl = c & 15;
    int slot = wv * 8 + gi * 2 + hu;
    base[(slot * 4 + quad) * 128 + nl * 8 + kl] = f2bf(v);
  }
}

// ---------------- x -> bf16 (+ zero the dummy rows of both buffers) ----------------
__global__ void k_convert(const float* __restrict__ x, u16* __restrict__ h0,
                          u16* __restrict__ h1) {
  int i = (blockIdx.x * 256 + threadIdx.x) * 4;
  float4 v = *(const float4*)(x + i);
  u16 o[4] = {f2bf(v.x), f2bf(v.y), f2bf(v.z), f2bf(v.w)};
  *(uint2*)(h0 + i) = *(uint2*)o;
  if (blockIdx.x == 0) {
    int t = threadIdx.x;
    if (t < 64)       ((u32*)(h0 + (size_t)N_NODES * 128))[t] = 0;
    else if (t < 128) ((u32*)(h1 + (size_t)N_NODES * 128))[t - 64] = 0;
  }
}

// ---------------- gather helpers ----------------
__device__ inline void acc8(f32x2* a, uint4 p) {
  f32x2 v;
  v.x = __uint_as_float(p.x << 16); v.y = __uint_as_float(p.x & 0xffff0000u);
  a[0] += v;
  v.x = __uint_as_float(p.y << 16); v.y = __uint_as_float(p.y & 0xffff0000u);
  a[1] += v;
  v.x = __uint_as_float(p.z << 16); v.y = __uint_as_float(p.z & 0xffff0000u);
  a[2] += v;
  v.x = __uint_as_float(p.w << 16); v.y = __uint_as_float(p.w & 0xffff0000u);
  a[3] += v;
}
__device__ inline uint4 ldrow(const char* hb, u32 off) {
  return *(const uint4*)(hb + off);
}

// ---------------- neighbor gather-sum: s[dst] = sum h[src] ----------------
// PAIR version: one wave owns TWO consecutive nodes; quarter-wave q walks
// edge slots j = beg + q + 4t for both nodes in one merged, fully-predicated
// loop -> 8 row-loads in flight per lane (2x the single-node version) at the
// same high occupancy. OOB slots redirect to the all-zero dummy row.
__global__ void k_gather(const u16* __restrict__ h, const int* __restrict__ csr,
                         const int* __restrict__ offs, u16* __restrict__ s) {
  int wave = threadIdx.x >> 6;
  int lane = threadIdx.x & 63;
  int q   = lane >> 4;
  int nl  = lane & 15;
  int nodeA = blockIdx.x * 8 + wave * 2;   // 12500 * 8 == 100000 exactly
  const char* hb = (const char*)h;
  const u32 co = (u32)(nl * 16);
  int o0 = offs[nodeA], o1 = offs[nodeA + 1], o2 = offs[nodeA + 2];
  f32x2 aA[4], aB[4];
  #pragma unroll
  for (int r = 0; r < 4; ++r) { aA[r] = (f32x2){0.f, 0.f}; aB[r] = (f32x2){0.f, 0.f}; }
  int jA = o0 + q, jB = o1 + q;
  int dmax = max(o1 - o0, o2 - o1);
  int iters = (dmax + 15) >> 4;
  #pragma unroll 1
  for (int t = 0; t < iters; ++t) {
    u32 sa[4], sb[4];
    #pragma unroll
    for (int k = 0; k < 4; ++k) {
      int jj = jA + 4 * k;
      u32 sv = (u32)csr[jj < o1 ? jj : 0];
      sa[k] = (jj < o1) ? sv : (u32)N_NODES;
      jj = jB + 4 * k;
      sv = (u32)csr[jj < o2 ? jj : 0];
      sb[k] = (jj < o2) ? sv : (u32)N_NODES;
    }
    uint4 pa0 = ldrow(hb, (sa[0] << 8) | co);
    uint4 pa1 = ldrow(hb, (sa[1] << 8) | co);
    uint4 pa2 = ldrow(hb, (sa[2] << 8) | co);
    uint4 pa3 = ldrow(hb, (sa[3] << 8) | co);
    uint4 pb0 = ldrow(hb, (sb[0] << 8) | co);
    uint4 pb1 = ldrow(hb, (sb[1] << 8) | co);
    uint4 pb2 = ldrow(hb, (sb[2] << 8) | co);
    uint4 pb3 = ldrow(hb, (sb[3] << 8) | co);
    acc8(aA, pa0); acc8(aA, pa1); acc8(aA, pa2); acc8(aA, pa3);
    acc8(aB, pb0); acc8(aB, pb1); acc8(aB, pb2); acc8(aB, pb3);
    jA += 16; jB += 16;
  }
  #pragma unroll
  for (int r = 0; r < 4; ++r) {
    aA[r].x += __shfl_xor(aA[r].x, 16); aA[r].x += __shfl_xor(aA[r].x, 32);
    aA[r].y += __shfl_xor(aA[r].y, 16); aA[r].y += __shfl_xor(aA[r].y, 32);
    aB[r].x += __shfl_xor(aB[r].x, 16); aB[r].x += __shfl_xor(aB[r].x, 32);
    aB[r].y += __shfl_xor(aB[r].y, 16); aB[r].y += __shfl_xor(aB[r].y, 32);
  }
  if (q < 2) {   // q==0 stores node A, q==1 stores node B (xor-reduce is full-wave)
    f32x2 w0 = q ? aB[0] : aA[0];
    f32x2 w1 = q ? aB[1] : aA[1];
    f32x2 w2 = q ? aB[2] : aA[2];
    f32x2 w3 = q ? aB[3] : aA[3];
    uint4 o;
    o.x = (u32)f2bf(w0.x) | ((u32)f2bf(w0.y) << 16);
    o.y = (u32)f2bf(w1.x) | ((u32)f2bf(w1.y) << 16);
    o.z = (u32)f2bf(w2.x) | ((u32)f2bf(w2.y) << 16);
    o.w = (u32)f2bf(w3.x) | ((u32)f2bf(w3.y) << 16);
    *(uint4*)(s + (size_t)(nodeA + q) * 128 + nl * 8) = o;
  }
}

// ---------------- fused dual-GEMM + GRU cell (R15-frozen) ----------------
__global__ __launch_bounds__(256, 2) void k_gemm_gru(
    const u16* __restrict__ s_mat, const u16* __restrict__ h_mat,
    const u16* __restrict__ bsw, const float* __restrict__ b_ih,
    const float* __restrict__ b_hh, u16* __restrict__ h_out) {
  __shared__ u16 Asw[8192];       // 16 KB: A=[s|h], 32 rows x 256 k, frag-ordered

  const int tid  = threadIdx.x;
  const int wave = tid >> 6;
  const int lane = tid & 63;
  const int nl   = lane & 15;
  const int quad = lane >> 4;
  const int row0 = blockIdx.x * 32;   // 3125 * 32 == 100000 exactly

  {  // stage A
    int snl = tid & 15, squad = (tid >> 4) & 3, sel = tid >> 6;
    int g = sel & 1, half = sel >> 1;
    const u16* row = (half ? h_mat : s_mat) + (size_t)(row0 + g * 16 + snl) * 128;
    #pragma unroll
    for (int kc2 = 0; kc2 < 4; ++kc2) {
      uint4 v = *(const uint4*)(row + kc2 * 32 + squad * 8);
      *(uint4*)&Asw[(((g * 8 + half * 4 + kc2) * 4 + squad) * 16 + snl) * 8] = v;
    }
  }
  __syncthreads();

  const u16* bp = bsw + wave * 8 * 512 + lane * 8;

  f32x4 acc[2][8];
  #pragma unroll
  for (int g = 0; g < 2; ++g)
    #pragma unroll
    for (int u = 0; u < 8; ++u) acc[g][u] = (f32x4){0.f, 0.f, 0.f, 0.f};

  bf16x8 b0[6], b1[6], b2[6];
  #pragma unroll
  for (int i = 0; i < 6; ++i) b0[i] = *(const bf16x8*)(bp + i * 512);
  #pragma unroll
  for (int i = 0; i < 6; ++i) b1[i] = *(const bf16x8*)(bp + 16384 + i * 512);

  #pragma unroll
  for (int kc = 0; kc < 8; ++kc) {
    if (kc < 6) {
      #pragma unroll
      for (int i = 0; i < 6; ++i) {
        int us = (kc + 2 < 4) ? i : (i < 4 ? i : i + 2);
        b2[i] = *(const bf16x8*)(bp + (kc + 2) * 16384 + us * 512);
      }
    }
    bf16x8 a0 = *(const bf16x8*)&Asw[kc * 512 + lane * 8];
    bf16x8 a1 = *(const bf16x8*)&Asw[(8 + kc) * 512 + lane * 8];
    #pragma unroll
    for (int i = 0; i < 6; ++i) {
      int u = (kc < 4) ? i : (i < 4 ? i : i + 2);
      acc[0][u] = __builtin_amdgcn_mfma_f32_16x16x32_bf16(a0, b0[i], acc[0][u], 0, 0, 0);
      acc[1][u] = __builtin_amdgcn_mfma_f32_16x16x32_bf16(a1, b0[i], acc[1][u], 0, 0, 0);
    }
    #pragma unroll
    for (int i = 0; i < 6; ++i) { b0[i] = b1[i]; b1[i] = b2[i]; }
  }

  float bias[8];
  #pragma unroll
  for (int u = 0; u < 8; ++u) {
    int gi = u >> 1, hu = u & 1;
    int cw = wave * 32 + hu * 16 + nl;
    bias[u] = (gi == 0) ? b_ih[cw] + b_hh[cw]
            : (gi == 1) ? b_ih[128 + cw] + b_hh[128 + cw]
            : (gi == 2) ? b_ih[256 + cw]
                        : b_hh[256 + cw];
  }

  #pragma unroll
  for (int g = 0; g < 2; ++g) {
    #pragma unroll
    for (int hu = 0; hu < 2; ++hu) {
      int cw = wave * 32 + hu * 16 + nl;
      int hbase = ((g * 8 + 4 + wave) * 4 + ((hu * 2 + (nl >> 3)) & 3)) * 128 + (nl & 7);
      #pragma unroll
      for (int i = 0; i < 4; ++i) {
        int m = quad * 4 + i;
        float rv = sig_f(acc[g][0 + hu][i] + bias[0 + hu]);
        float zv = sig_f(acc[g][2 + hu][i] + bias[2 + hu]);
        float iv = acc[g][4 + hu][i] + bias[4 + hu];
        float hn = acc[g][6 + hu][i] + bias[6 + hu];
        float hv = bf2f(Asw[hbase + m * 8]);
        float n  = tanh_f(iv + rv * hn);
        float o  = n + zv * (hv - n);
        h_out[(size_t)(row0 + g * 16 + m) * 128 + cw] = f2bf(o);
      }
    }
  }
}

// ---------------- relu + segment mean pool (two-phase, parallel) ----------------
__global__ void k_pool_partial(const u16* __restrict__ h, const int* __restrict__ batch,
                               float* __restrict__ acc) {
  int t = threadIdx.x;  // column 0..127
  int node0 = blockIdx.x * 125;
  int node1 = node0 + 125;
  int cur = batch[node0];
  float sum = 0.f;
  for (int r = node0; r < node1; ++r) {
    int g = batch[r];
    if (g != cur) {
      atomicAdd(&acc[cur * 128 + t], sum);
      sum = 0.f;
      cur = g;
    }
    sum += fmaxf(bf2f(h[(size_t)r * 128 + t]), 0.f);
  }
  atomicAdd(&acc[cur * 128 + t], sum);
}

__global__ void k_pool_div(const float* __restrict__ acc, const int* __restrict__ batch,
                           float* __restrict__ out) {
  __shared__ int se[2];
  int g = blockIdx.x, t = threadIdx.x;
  if (t < 2) {
    int target = g + t;
    int lo = 0, hi = N_NODES;
    while (lo < hi) { int mid = (lo + hi) >> 1; if (batch[mid] < target) lo = mid + 1; else hi = mid; }
    se[t] = lo;
  }
  __syncthreads();
  int cnt = se[1] - se[0];
  out[g * 128 + t] = acc[g * 128 + t] / (float)(cnt > 0 ? cnt : 1);
}

extern "C" void kernel_launch(void* const* d_in, const int* in_sizes, int n_in,
                              void* d_out, int out_size, void* d_ws, size_t ws_size,
                              hipStream_t stream) {
  const float* x     = (const float*)d_in[0];
  const int*   edges = (const int*)d_in[1];
  const int*   batch = (const int*)d_in[2];
  const float* W     = (const float*)d_in[3];
  const float* w_ih  = (const float*)d_in[4];
  const float* w_hh  = (const float*)d_in[5];
  const float* b_ih  = (const float*)d_in[6];
  const float* b_hh  = (const float*)d_in[7];
  float* out = (float*)d_out;

  char* w = (char*)d_ws;
  u16* buf0    = (u16*)(w);                 // 25,600,256 B (h/s ping + zero dummy row)
  u16* buf1    = (u16*)(w + 25600256);      // 25,600,256 B (h/s pong + zero dummy row)
  u16* bsw     = (u16*)(w + 51200512);      // 1,048,576 B
  float* acc   = (float*)(w + 52249088);    // 32,768 B  (pool accumulator)
  int* offs    = (int*)(w + 52281856);      // 400,004 B
  int* gcursor = (int*)(w + 52682240);      // 1,024 B
  int* ebase   = (int*)(w + 52683264);      // 1,028 B
  int* csr     = (int*)(w + 52684800);      // 6,400,000 B -> total ~59.1 MB
  u32* ebuf    = (u32*)buf1;                // 7.3 MB; no overlap with buf1 dummy row

  const int* esrc = edges;
  const int* edst = edges + N_EDGES;

  hipMemsetAsync(gcursor, 0, NBUCK * sizeof(int), stream);
  k_part<<<391, 1024, 0, stream>>>(esrc, edst, gcursor, ebuf);
  k_bscan<<<1, NBUCK, 0, stream>>>(gcursor, ebase, acc);
  k_csr<<<NBUCK, 1024, 0, stream>>>(ebuf, ebase, offs, csr);
  k_wb<<<1024, 128, 0, stream>>>(W, w_ih, w_hh, bsw);
  k_convert<<<(N_NODES * HIDDEN) / 1024, 256, 0, stream>>>(x, buf0, buf1);

  u16* hcur = buf0;
  u16* hnxt = buf1;
  for (int st = 0; st < STEPS; ++st) {
    k_gather<<<N_NODES / 8, 256, 0, stream>>>(hcur, csr, offs, hnxt);
    // in-place: each block reads only its own 32 rows of s (hnxt) and h (hcur)
    // into LDS before writing h_out (hnxt) over those same rows.
    k_gemm_gru<<<N_NODES / 32, 256, 0, stream>>>(hnxt, hcur, bsw + st * 131072,
                                                 b_ih, b_hh, hnxt);
    u16* tmp = hcur; hcur = hnxt; hnxt = tmp;
  }
  k_pool_partial<<<800, 128, 0, stream>>>(hcur, batch, acc);
  k_pool_div<<<N_GRAPHS, 128, 0, stream>>>(acc, batch, out);
}

// Round 8
// 540.912 us; speedup vs baseline: 1.0777x; 1.0777x over previous
//
#include <hip/hip_runtime.h>

#define N_NODES  100000
#define N_EDGES  1600000
#define HIDDEN   128
#define STEPS    4
#define N_GRAPHS 64
#define NBUCK    256
#define BWID     391   // nodes per bucket: 256*391 = 100096 >= 100000 (<512 -> 9 bits)
#define BCAP     7168  // fixed ebuf slots per bucket (mean 6250, +11 sigma)

typedef unsigned short u16;
typedef unsigned int   u32;
typedef unsigned long long u64;
typedef __attribute__((ext_vector_type(8))) short bf16x8;
typedef __attribute__((ext_vector_type(4))) float f32x4;
typedef __attribute__((ext_vector_type(2))) float f32x2;

__device__ inline u16 f2bf(float f) {
  u32 u = __float_as_uint(f);
  u = (u + 0x7FFFu + ((u >> 16) & 1u)) >> 16;  // RTNE
  return (u16)u;
}
__device__ inline float bf2f(u16 b) { return __uint_as_float(((u32)b) << 16); }

// rcp-based activations: no IEEE division sequence, no clamps.
__device__ inline float rcp_f(float x) { return __builtin_amdgcn_rcpf(x); }
__device__ inline float sig_f(float x) { return rcp_f(1.f + __expf(-x)); }
__device__ inline float tanh_f(float x) { return 1.f - 2.f * rcp_f(1.f + __expf(2.f * x)); }

// LDS XOR-swizzle (involution on byte address): spreads the gather's
// stride-256B fragment writes across 8 bank groups. Bits[6:4] ^= bits[10:8].
__device__ inline u32 swz(u32 b) { return b ^ (((b >> 8) & 7u) << 4); }

// ---------------- CSR build (bucketed multisplit, fixed-capacity buckets) ----------------
__global__ __launch_bounds__(1024) void k_part(const int* __restrict__ esrc,
                                               const int* __restrict__ edst,
                                               int* __restrict__ gcursor,
                                               u32* __restrict__ ebuf) {
  __shared__ int hist[16][NBUCK];   // 16 KB
  __shared__ int base[16][NBUCK];   // 16 KB
  int tid = threadIdx.x;
  int wv  = tid >> 6;
  #pragma unroll
  for (int i = 0; i < 4; ++i) ((int*)hist)[tid + i * 1024] = 0;
  __syncthreads();
  int e0 = blockIdx.x * 4096;
  int sv[4], dv[4], bk[4], rk[4];
  #pragma unroll
  for (int i = 0; i < 4; ++i) {
    int e = e0 + i * 1024 + tid;
    if (e < N_EDGES) {
      sv[i] = esrc[e];
      dv[i] = edst[e];
      bk[i] = (int)((u32)dv[i] / (u32)BWID);
      rk[i] = atomicAdd(&hist[wv][bk[i]], 1);
    } else bk[i] = -1;
  }
  __syncthreads();
  if (tid < NBUCK) {
    int c[16];
    int sum = 0;
    #pragma unroll
    for (int w = 0; w < 16; ++w) { c[w] = hist[w][tid]; sum += c[w]; }
    int g = atomicAdd(&gcursor[tid], sum);
    #pragma unroll
    for (int w = 0; w < 16; ++w) { base[w][tid] = g; g += c[w]; }
  }
  __syncthreads();
  #pragma unroll
  for (int i = 0; i < 4; ++i) {
    if (bk[i] >= 0) {
      int pos = bk[i] * BCAP + base[wv][bk[i]] + rk[i];
      ebuf[pos] = ((u32)(dv[i] - bk[i] * BWID) << 17) | (u32)sv[i];
    }
  }
}

// Scan bucket counts -> ebase; also zero the pool accumulator (saves a dispatch).
__global__ void k_bscan(const int* __restrict__ gcursor, int* __restrict__ ebase,
                        float* __restrict__ acc) {
  __shared__ int buf[NBUCK];
  int t = threadIdx.x;
  int v = gcursor[t];
  buf[t] = v;
  __syncthreads();
  for (int off = 1; off < NBUCK; off <<= 1) {
    int u = 0;
    if (t >= off) u = buf[t - off];
    __syncthreads();
    buf[t] += u;
    __syncthreads();
  }
  ebase[t] = buf[t] - v;
  if (t == NBUCK - 1) ebase[NBUCK] = buf[t];
  for (int i = t; i < N_GRAPHS * HIDDEN; i += NBUCK) acc[i] = 0.f;
}

__global__ __launch_bounds__(1024) void k_csr(const u32* __restrict__ ebuf,
                                              const int* __restrict__ ebase,
                                              int* __restrict__ offs,
                                              int* __restrict__ csr) {
  __shared__ int lcnt[512];
  __shared__ int lofs[512];
  int b = blockIdx.x, tid = threadIdx.x;
  int n0 = b * BWID;
  int n1 = min(n0 + BWID, N_NODES);
  int nn = n1 - n0;
  int e0 = ebase[b];
  int cnt = ebase[b + 1] - e0;
  const u32* ebase_p = ebuf + (size_t)b * BCAP;
  if (tid < 512) lcnt[tid] = 0;
  __syncthreads();
  for (int e = tid; e < cnt; e += 1024) {
    int dst = (int)(ebase_p[e] >> 17);   // bucket-local
    atomicAdd(&lcnt[dst], 1);
  }
  __syncthreads();
  if (tid < 512) lofs[tid] = lcnt[tid];
  __syncthreads();
  for (int off = 1; off < 512; off <<= 1) {
    int v = 0;
    if (tid < 512 && tid >= off) v = lofs[tid - off];
    __syncthreads();
    if (tid < 512 && tid >= off) lofs[tid] += v;
    __syncthreads();
  }
  int nodeoff = 0;
  if (tid < 512) nodeoff = e0 + lofs[tid] - lcnt[tid];  // exclusive
  if (tid < 512) lofs[tid] = nodeoff;                   // reuse as cursor
  if (tid < nn) offs[n0 + tid] = nodeoff;
  if (b == 0 && tid == 0) offs[N_NODES] = N_EDGES;
  __syncthreads();
  for (int e = tid; e < cnt; e += 1024) {
    u32 p = ebase_p[e];
    int src = (int)(p & 0x1FFFFu);
    int dst = (int)(p >> 17);
    int pos = atomicAdd(&lofs[dst], 1);
    csr[pos] = src;
  }
}

// ---------------- combined weight build + x->bf16 convert (merged dispatch) ----------------
// Blocks [0,1024): weight build (128 active threads). Blocks [1024, 1024+12500): convert.
__global__ void k_wbc(const float* __restrict__ W, const float* __restrict__ w_ih,
                      const float* __restrict__ w_hh, u16* __restrict__ bsw,
                      const float* __restrict__ x, u16* __restrict__ h0,
                      u16* __restrict__ h1) {
  __shared__ float wrow[128];
  if (blockIdx.x >= 1024) {
    int bb = blockIdx.x - 1024;
    int i = (bb * 256 + threadIdx.x) * 4;
    float4 v = *(const float4*)(x + i);
    u16 o[4] = {f2bf(v.x), f2bf(v.y), f2bf(v.z), f2bf(v.w)};
    *(uint2*)(h0 + i) = *(uint2*)o;
    if (bb == 0) {
      int t = threadIdx.x;
      if (t < 64)       ((u32*)(h0 + (size_t)N_NODES * 128))[t] = 0;
      else if (t < 128) ((u32*)(h1 + (size_t)N_NODES * 128))[t - 64] = 0;
    }
    return;
  }
  int b = blockIdx.x, st = b >> 8, k = b & 255, t = threadIdx.x;
  if (t >= 128) return;
  if (k < 128) wrow[t] = W[(st * 128 + k) * 128 + t];
  __syncthreads();
  int kc = k >> 5, quad = (k >> 3) & 3, kl = k & 7;
  u16* base = bsw + (size_t)st * 131072 + kc * 16384;
  #pragma unroll
  for (int gq = 0; gq < 4; ++gq) {
    int c = gq * 128 + t;
    float v;
    if (k < 128) {
      if (c < 384) {
        const float* wr = w_ih + c * 128;
        float sacc = 0.f;
        for (int j = 0; j < 128; ++j) sacc += wrow[j] * wr[j];
        v = sacc;
      } else v = 0.f;
    } else {
      int kk = k - 128;
      if (c < 256)      v = w_hh[c * 128 + kk];
      else if (c < 384) v = 0.f;
      else              v = w_hh[(c - 128) * 128 + kk];
    }
    int gi = c >> 7, cw = c & 127;
    int wv = cw >> 5, hu = (cw >> 4) & 1, nl = c & 15;
    int slot = wv * 8 + gi * 2 + hu;
    base[(slot * 4 + quad) * 128 + nl * 8 + kl] = f2bf(v);
  }
}

// ---------------- gather helpers ----------------
__device__ inline void acc8(f32x2* a, uint4 p) {
  f32x2 v;
  v.x = __uint_as_float(p.x << 16); v.y = __uint_as_float(p.x & 0xffff0000u);
  a[0] += v;
  v.x = __uint_as_float(p.y << 16); v.y = __uint_as_float(p.y & 0xffff0000u);
  a[1] += v;
  v.x = __uint_as_float(p.z << 16); v.y = __uint_as_float(p.z & 0xffff0000u);
  a[2] += v;
  v.x = __uint_as_float(p.w << 16); v.y = __uint_as_float(p.w & 0xffff0000u);
  a[3] += v;
}
__device__ inline uint4 ldrow(const char* hb, u32 off) {
  return *(const uint4*)(hb + off);
}

// ---------------- FUSED v4: R2's verified kernel + LDS-cached offs ----------------
// Identical to the 569us R2 kernel except: all 33 CSR offsets preloaded into LDS
// during the staging phase (one extra barrier), removing three dependent global
// loads from the serial critical path at the start of every node-pair.
__global__ __launch_bounds__(256, 3) void k_fused(
    const u16* __restrict__ h_mat, const int* __restrict__ csr,
    const int* __restrict__ offs, const u16* __restrict__ bsw,
    const float* __restrict__ b_ih, const float* __restrict__ b_hh,
    u16* __restrict__ h_out) {
  __shared__ u16 Asw[8192];       // 16 KB: A=[s|h], 32 rows x 256 k, frag-ordered
  __shared__ int soffs[33];
  char* lds = (char*)Asw;

  const int tid  = threadIdx.x;
  const int wave = tid >> 6;
  const int lane = tid & 63;
  const int nl   = lane & 15;
  const int quad = lane >> 4;
  const int row0 = blockIdx.x * 32;   // 3125 * 32 == 100000 exactly

  if (tid < 33) soffs[tid] = offs[row0 + tid];

  {  // stage h half (own rows, coalesced): all 4 waves, 2 uint4/thread
    int snl = tid & 15, squad = (tid >> 4) & 3, w = tid >> 6;
    int g = w & 1;
    const u16* row = h_mat + (size_t)(row0 + g * 16 + snl) * 128;
    #pragma unroll
    for (int kk = 0; kk < 2; ++kk) {
      int kc2 = (w >> 1) * 2 + kk;
      uint4 v = *(const uint4*)(row + kc2 * 32 + squad * 8);
      u32 b = (u32)(((g * 8 + 4 + kc2) * 4 + squad) * 256 + snl * 16);
      *(uint4*)(lds + swz(b)) = v;
    }
  }
  __syncthreads();   // soffs (and staged h) visible to all

  {  // gather: 4 node-pairs per wave, merged predicated loop, 8 rows/group
    const char* hb = (const char*)h_mat;
    const int q   = quad;
    const u32 co  = (u32)(nl * 16);
    #pragma unroll 1
    for (int p = 0; p < 4; ++p) {
      int nA = wave * 8 + p * 2;
      int o0 = soffs[nA], o1 = soffs[nA + 1], o2 = soffs[nA + 2];
      f32x2 aA[4], aB[4];
      #pragma unroll
      for (int r = 0; r < 4; ++r) { aA[r] = (f32x2){0.f, 0.f}; aB[r] = (f32x2){0.f, 0.f}; }
      int jA = o0 + q, jB = o1 + q;
      int dmax = max(o1 - o0, o2 - o1);
      int iters = (dmax + 15) >> 4;
      #pragma unroll 1
      for (int t = 0; t < iters; ++t) {
        u32 sa[4], sb[4];
        #pragma unroll
        for (int k = 0; k < 4; ++k) {
          int jj = jA + 4 * k;
          u32 sv = (u32)csr[jj < o1 ? jj : 0];
          sa[k] = (jj < o1) ? sv : (u32)N_NODES;
          jj = jB + 4 * k;
          sv = (u32)csr[jj < o2 ? jj : 0];
          sb[k] = (jj < o2) ? sv : (u32)N_NODES;
        }
        uint4 pa0 = ldrow(hb, (sa[0] << 8) | co);
        uint4 pa1 = ldrow(hb, (sa[1] << 8) | co);
        uint4 pa2 = ldrow(hb, (sa[2] << 8) | co);
        uint4 pa3 = ldrow(hb, (sa[3] << 8) | co);
        uint4 pb0 = ldrow(hb, (sb[0] << 8) | co);
        uint4 pb1 = ldrow(hb, (sb[1] << 8) | co);
        uint4 pb2 = ldrow(hb, (sb[2] << 8) | co);
        uint4 pb3 = ldrow(hb, (sb[3] << 8) | co);
        acc8(aA, pa0); acc8(aA, pa1); acc8(aA, pa2); acc8(aA, pa3);
        acc8(aB, pb0); acc8(aB, pb1); acc8(aB, pb2); acc8(aB, pb3);
        jA += 16; jB += 16;
      }
      #pragma unroll
      for (int r = 0; r < 4; ++r) {
        aA[r].x += __shfl_xor(aA[r].x, 16); aA[r].x += __shfl_xor(aA[r].x, 32);
        aA[r].y += __shfl_xor(aA[r].y, 16); aA[r].y += __shfl_xor(aA[r].y, 32);
        aB[r].x += __shfl_xor(aB[r].x, 16); aB[r].x += __shfl_xor(aB[r].x, 32);
        aB[r].y += __shfl_xor(aB[r].y, 16); aB[r].y += __shfl_xor(aB[r].y, 32);
      }
      if (q < 2) {  // q==0 writes node A, q==1 writes node B (xor-reduce is full-wave)
        f32x2 w0 = q ? aB[0] : aA[0];
        f32x2 w1 = q ? aB[1] : aA[1];
        f32x2 w2 = q ? aB[2] : aA[2];
        f32x2 w3 = q ? aB[3] : aA[3];
        uint4 o;
        o.x = (u32)f2bf(w0.x) | ((u32)f2bf(w0.y) << 16);
        o.y = (u32)f2bf(w1.x) | ((u32)f2bf(w1.y) << 16);
        o.z = (u32)f2bf(w2.x) | ((u32)f2bf(w2.y) << 16);
        o.w = (u32)f2bf(w3.x) | ((u32)f2bf(w3.y) << 16);
        int n = nA + q, g = n >> 4, snl = n & 15;
        u32 b = (u32)(g * 8192 + nl * 256 + snl * 16);
        *(uint4*)(lds + swz(b)) = o;
      }
    }
  }
  __syncthreads();

  // ---- dual-GEMM + GRU cell (R15-frozen, swizzled A reads) ----
  const u16* bp = bsw + wave * 8 * 512 + lane * 8;

  f32x4 acc[2][8];
  #pragma unroll
  for (int g = 0; g < 2; ++g)
    #pragma unroll
    for (int u = 0; u < 8; ++u) acc[g][u] = (f32x4){0.f, 0.f, 0.f, 0.f};

  bf16x8 b0[6], b1[6], b2[6];
  #pragma unroll
  for (int i = 0; i < 6; ++i) b0[i] = *(const bf16x8*)(bp + i * 512);
  #pragma unroll
  for (int i = 0; i < 6; ++i) b1[i] = *(const bf16x8*)(bp + 16384 + i * 512);

  #pragma unroll
  for (int kc = 0; kc < 8; ++kc) {
    if (kc < 6) {
      #pragma unroll
      for (int i = 0; i < 6; ++i) {
        int us = (kc + 2 < 4) ? i : (i < 4 ? i : i + 2);
        b2[i] = *(const bf16x8*)(bp + (kc + 2) * 16384 + us * 512);
      }
    }
    bf16x8 a0 = *(const bf16x8*)(lds + swz((u32)(kc * 1024 + lane * 16)));
    bf16x8 a1 = *(const bf16x8*)(lds + swz((u32)((8 + kc) * 1024 + lane * 16)));
    #pragma unroll
    for (int i = 0; i < 6; ++i) {
      int u = (kc < 4) ? i : (i < 4 ? i : i + 2);
      acc[0][u] = __builtin_amdgcn_mfma_f32_16x16x32_bf16(a0, b0[i], acc[0][u], 0, 0, 0);
      acc[1][u] = __builtin_amdgcn_mfma_f32_16x16x32_bf16(a1, b0[i], acc[1][u], 0, 0, 0);
    }
    #pragma unroll
    for (int i = 0; i < 6; ++i) { b0[i] = b1[i]; b1[i] = b2[i]; }
  }

  float bias[8];
  #pragma unroll
  for (int u = 0; u < 8; ++u) {
    int gi = u >> 1, hu = u & 1;
    int cw = wave * 32 + hu * 16 + nl;
    bias[u] = (gi == 0) ? b_ih[cw] + b_hh[cw]
            : (gi == 1) ? b_ih[128 + cw] + b_hh[128 + cw]
            : (gi == 2) ? b_ih[256 + cw]
                        : b_hh[256 + cw];
  }

  #pragma unroll
  for (int g = 0; g < 2; ++g) {
    #pragma unroll
    for (int hu = 0; hu < 2; ++hu) {
      int cw = wave * 32 + hu * 16 + nl;
      u32 hslot = (u32)((g * 8 + 4 + wave) * 4 + ((hu * 2 + (nl >> 3)) & 3));
      #pragma unroll
      for (int i = 0; i < 4; ++i) {
        int m = quad * 4 + i;
        float rv = sig_f(acc[g][0 + hu][i] + bias[0 + hu]);
        float zv = sig_f(acc[g][2 + hu][i] + bias[2 + hu]);
        float iv = acc[g][4 + hu][i] + bias[4 + hu];
        float hn = acc[g][6 + hu][i] + bias[6 + hu];
        u32 hb2 = hslot * 256 + (u32)m * 16 + (u32)(nl & 7) * 2;
        float hv = bf2f(*(const u16*)(lds + swz(hb2)));
        float n  = tanh_f(iv + rv * hn);
        float o  = n + zv * (hv - n);
        h_out[(size_t)(row0 + g * 16 + m) * 128 + cw] = f2bf(o);
      }
    }
  }
}

// ---------------- relu + segment mean pool (two-phase, parallel) ----------------
__global__ void k_pool_partial(const u16* __restrict__ h, const int* __restrict__ batch,
                               float* __restrict__ acc) {
  int t = threadIdx.x;  // column 0..127
  int node0 = blockIdx.x * 80;
  int node1 = node0 + 80;
  int cur = batch[node0];
  float sum = 0.f;
  for (int r = node0; r < node1; ++r) {
    int g = batch[r];
    if (g != cur) {
      atomicAdd(&acc[cur * 128 + t], sum);
      sum = 0.f;
      cur = g;
    }
    sum += fmaxf(bf2f(h[(size_t)r * 128 + t]), 0.f);
  }
  atomicAdd(&acc[cur * 128 + t], sum);
}

__global__ void k_pool_div(const float* __restrict__ acc, const int* __restrict__ batch,
                           float* __restrict__ out) {
  __shared__ int se[2];
  int g = blockIdx.x, t = threadIdx.x;
  if (t < 2) {
    int target = g + t;
    int lo = 0, hi = N_NODES;
    while (lo < hi) { int mid = (lo + hi) >> 1; if (batch[mid] < target) lo = mid + 1; else hi = mid; }
    se[t] = lo;
  }
  __syncthreads();
  int cnt = se[1] - se[0];
  out[g * 128 + t] = acc[g * 128 + t] / (float)(cnt > 0 ? cnt : 1);
}

extern "C" void kernel_launch(void* const* d_in, const int* in_sizes, int n_in,
                              void* d_out, int out_size, void* d_ws, size_t ws_size,
                              hipStream_t stream) {
  const float* x     = (const float*)d_in[0];
  const int*   edges = (const int*)d_in[1];
  const int*   batch = (const int*)d_in[2];
  const float* W     = (const float*)d_in[3];
  const float* w_ih  = (const float*)d_in[4];
  const float* w_hh  = (const float*)d_in[5];
  const float* b_ih  = (const float*)d_in[6];
  const float* b_hh  = (const float*)d_in[7];
  float* out = (float*)d_out;

  char* w = (char*)d_ws;
  u16* buf0    = (u16*)(w);                 // 25,600,256 B (h ping + zero dummy row)
  u16* buf1    = (u16*)(w + 25600256);      // 25,600,256 B (h pong + zero dummy row)
  u16* bsw     = (u16*)(w + 51200512);      // 1,048,576 B
  float* acc   = (float*)(w + 52249088);    // 32,768 B  (pool accumulator)
  int* offs    = (int*)(w + 52281856);      // 400,004 B
  int* gcursor = (int*)(w + 52682240);      // 1,024 B
  int* ebase   = (int*)(w + 52683264);      // 1,028 B
  int* csr     = (int*)(w + 52684800);      // 6,400,000 B -> total ~59.1 MB
  u32* ebuf    = (u32*)buf1;                // 7.3 MB; fully consumed before buf1 h-use

  const int* esrc = edges;
  const int* edst = edges + N_EDGES;

  hipMemsetAsync(gcursor, 0, NBUCK * sizeof(int), stream);
  k_part<<<391, 1024, 0, stream>>>(esrc, edst, gcursor, ebuf);
  k_bscan<<<1, NBUCK, 0, stream>>>(gcursor, ebase, acc);
  k_csr<<<NBUCK, 1024, 0, stream>>>(ebuf, ebase, offs, csr);
  k_wbc<<<1024 + (N_NODES * HIDDEN) / 1024, 256, 0, stream>>>(W, w_ih, w_hh, bsw,
                                                              x, buf0, buf1);

  u16* hcur = buf0;
  u16* hnxt = buf1;
  for (int st = 0; st < STEPS; ++st) {
    // ping-pong: gather reads random rows of hcur; output written to hnxt only.
    k_fused<<<N_NODES / 32, 256, 0, stream>>>(hcur, csr, offs, bsw + st * 131072,
                                              b_ih, b_hh, hnxt);
    u16* tmp = hcur; hcur = hnxt; hnxt = tmp;
  }
  k_pool_partial<<<1250, 128, 0, stream>>>(hcur, batch, acc);
  k_pool_div<<<N_GRAPHS, 128, 0, stream>>>(acc, batch, out);
}